// Round 1
// baseline (433.333 us; speedup 1.0000x reference)
//
#include <hip/hip_runtime.h>
#include <hip/hip_bf16.h>

#define N_NODES 4096
#define BATCH 16
#define IN_CH 128
#define HID 8
#define HEADS 4
#define F1 (HEADS*HID)   // 32
#define OUT_CH 64

// ---------------- CSR build ----------------
__global__ void k_zero(int* counts, int* cursor) {
    int i = blockIdx.x * 256 + threadIdx.x;
    if (i < N_NODES) { counts[i] = 0; cursor[i] = 0; }
}

__global__ void k_count(const int* __restrict__ dstA, int E, int* counts) {
    int e = blockIdx.x * 256 + threadIdx.x;
    if (e < E) atomicAdd(&counts[dstA[e]], 1);
}

// exclusive prefix sum over counts[0..4095] -> rowstart[0..4096]; single block of 256
__global__ void k_scan(const int* __restrict__ counts, int* rowstart) {
    __shared__ int part[256];
    int t = threadIdx.x;
    int base = t * 16;
    int local[16];
    int s = 0;
    #pragma unroll
    for (int i = 0; i < 16; i++) { local[i] = s; s += counts[base + i]; }
    part[t] = s;
    __syncthreads();
    for (int off = 1; off < 256; off <<= 1) {
        int v = (t >= off) ? part[t - off] : 0;
        __syncthreads();
        part[t] += v;
        __syncthreads();
    }
    int prev = (t == 0) ? 0 : part[t - 1];
    #pragma unroll
    for (int i = 0; i < 16; i++) rowstart[base + i] = prev + local[i];
    if (t == 255) rowstart[N_NODES] = part[255];
}

__global__ void k_fill(const int* __restrict__ srcA, const int* __restrict__ dstA, int E,
                       const int* __restrict__ rowstart, int* cursor, int* nbr) {
    int e = blockIdx.x * 256 + threadIdx.x;
    if (e < E) {
        int n = dstA[e];
        int pos = atomicAdd(&cursor[n], 1);
        nbr[rowstart[n] + pos] = srcA[e];
    }
}

// ---------------- Layer 1 projection: feat1 = x_b @ W1, el1/er1 ----------------
__global__ __launch_bounds__(256) void k_feat1(const float* __restrict__ x,
                                               const float* __restrict__ W1,
                                               const float* __restrict__ al1,
                                               const float* __restrict__ ar1,
                                               float* __restrict__ feat1,
                                               float* __restrict__ el1,
                                               float* __restrict__ er1) {
    __shared__ float lW1[IN_CH * F1];   // 16 KB
    __shared__ float lal[F1], lar[F1];
    int t = threadIdx.x;
    for (int i = t; i < IN_CH * F1; i += 256) lW1[i] = W1[i];
    if (t < F1) { lal[t] = al1[t]; lar[t] = ar1[t]; }
    __syncthreads();

    int b = blockIdx.y;
    int n = blockIdx.x * 256 + t;
    const float* xp = x + (size_t)b * IN_CH * N_NODES + n;

    float acc[F1];
    #pragma unroll
    for (int k = 0; k < F1; k++) acc[k] = 0.f;
    for (int c = 0; c < IN_CH; c++) {
        float xv = xp[(size_t)c * N_NODES];
        #pragma unroll
        for (int k = 0; k < F1; k++) acc[k] += xv * lW1[c * F1 + k];
    }
    size_t row = (size_t)b * N_NODES + n;
    float* fp = feat1 + row * F1;
    #pragma unroll
    for (int k = 0; k < F1; k++) fp[k] = acc[k];
    #pragma unroll
    for (int h = 0; h < HEADS; h++) {
        float el = 0.f, er = 0.f;
        #pragma unroll
        for (int d = 0; d < HID; d++) {
            el += acc[h * HID + d] * lal[h * HID + d];
            er += acc[h * HID + d] * lar[h * HID + d];
        }
        el1[row * HEADS + h] = el;
        er1[row * HEADS + h] = er;
    }
}

// ---------------- Layer 1 attention + bias + mish ----------------
__global__ __launch_bounds__(256) void k_attn1(const float* __restrict__ el1,
                                               const float* __restrict__ er1,
                                               const float* __restrict__ feat1,
                                               const int* __restrict__ rowstart,
                                               const int* __restrict__ nbr,
                                               const float* __restrict__ b1v,
                                               float* __restrict__ h1) {
    int t = threadIdx.x;
    int h = t & 3;
    int n = blockIdx.x * 64 + (t >> 2);
    int b = blockIdx.y;
    size_t brow = (size_t)b * N_NODES;
    int r0 = rowstart[n], r1 = rowstart[n + 1];
    float ern = er1[(brow + n) * HEADS + h];
    float den = 0.f;
    float acc[HID];
    #pragma unroll
    for (int d = 0; d < HID; d++) acc[d] = 0.f;
    for (int i = r0; i < r1; i++) {
        int s = nbr[i];
        float e = el1[(brow + s) * HEADS + h] + ern;
        e = (e > 0.f) ? e : 0.2f * e;
        float w = __expf(e);
        den += w;
        const float* fsp = feat1 + (brow + s) * F1 + h * HID;
        #pragma unroll
        for (int d = 0; d < HID; d++) acc[d] += w * fsp[d];
    }
    float inv = 1.f / den;
    float* hp = h1 + (brow + n) * F1 + h * HID;
    #pragma unroll
    for (int d = 0; d < HID; d++) {
        float v = acc[d] * inv + b1v[h * HID + d];
        float sp = log1pf(__expf(v));     // softplus
        hp[d] = v * tanhf(sp);            // mish
    }
}

// ---------------- Layer 2 projection: feat2 = h1 @ W2, el2/er2 ----------------
__global__ __launch_bounds__(256) void k_feat2(const float* __restrict__ h1,
                                               const float* __restrict__ W2,
                                               const float* __restrict__ al2,
                                               const float* __restrict__ ar2,
                                               float* __restrict__ feat2,
                                               float* __restrict__ el2,
                                               float* __restrict__ er2) {
    __shared__ float lW2[F1 * OUT_CH];   // 8 KB
    int t = threadIdx.x;
    for (int i = t; i < F1 * OUT_CH; i += 256) lW2[i] = W2[i];
    __syncthreads();
    int lane = t & 63;
    int n = blockIdx.x * 4 + (t >> 6);
    int b = blockIdx.y;
    size_t row = (size_t)b * N_NODES + n;
    const float* hp = h1 + row * F1;
    float hval = (lane < F1) ? hp[lane] : 0.f;
    float acc = 0.f;
    #pragma unroll
    for (int k = 0; k < F1; k++) {
        float hv = __shfl(hval, k, 64);
        acc += hv * lW2[k * OUT_CH + lane];
    }
    feat2[row * OUT_CH + lane] = acc;
    float pl = acc * al2[lane];
    float pr = acc * ar2[lane];
    #pragma unroll
    for (int off = 32; off > 0; off >>= 1) {
        pl += __shfl_xor(pl, off, 64);
        pr += __shfl_xor(pr, off, 64);
    }
    if (lane == 0) { el2[row] = pl; er2[row] = pr; }
}

// ---------------- Layer 2 attention + bias ----------------
__global__ __launch_bounds__(256) void k_attn2(const float* __restrict__ el2,
                                               const float* __restrict__ er2,
                                               const float* __restrict__ feat2,
                                               const int* __restrict__ rowstart,
                                               const int* __restrict__ nbr,
                                               const float* __restrict__ b2v,
                                               float* __restrict__ out2) {
    int t = threadIdx.x;
    int lane = t & 63;
    int n = blockIdx.x * 4 + (t >> 6);
    int b = blockIdx.y;
    size_t brow = (size_t)b * N_NODES;
    int r0 = rowstart[n], r1 = rowstart[n + 1];
    float ern = er2[brow + n];
    float den = 0.f, acc = 0.f;
    for (int i = r0; i < r1; i++) {
        int s = nbr[i];
        float e = el2[brow + s] + ern;
        e = (e > 0.f) ? e : 0.2f * e;
        float w = __expf(e);
        den += w;
        acc += w * feat2[(brow + s) * OUT_CH + lane];
    }
    out2[(brow + n) * OUT_CH + lane] = acc / den + b2v[lane];
}

// ---------------- transpose (b, n, o) -> (b, o, n) ----------------
__global__ __launch_bounds__(256) void k_trans(const float* __restrict__ out2,
                                               float* __restrict__ out) {
    __shared__ float tile[64][65];
    int t = threadIdx.x;
    int lane = t & 63, w = t >> 6;
    int n0 = blockIdx.x * 64;
    int b = blockIdx.y;
    const float* src = out2 + ((size_t)b * N_NODES + n0) * OUT_CH;
    #pragma unroll
    for (int i = 0; i < 16; i++) {
        int r = i * 4 + w;
        tile[r][lane] = src[(size_t)r * OUT_CH + lane];
    }
    __syncthreads();
    float* dst = out + (size_t)b * OUT_CH * N_NODES + n0;
    #pragma unroll
    for (int i = 0; i < 16; i++) {
        int o = i * 4 + w;
        dst[(size_t)o * N_NODES + lane] = tile[lane][o];
    }
}

extern "C" void kernel_launch(void* const* d_in, const int* in_sizes, int n_in,
                              void* d_out, int out_size, void* d_ws, size_t ws_size,
                              hipStream_t stream) {
    const float* x   = (const float*)d_in[0];
    const float* W1  = (const float*)d_in[1];
    const float* al1 = (const float*)d_in[2];
    const float* ar1 = (const float*)d_in[3];
    const float* b1v = (const float*)d_in[4];
    const float* W2  = (const float*)d_in[5];
    const float* al2 = (const float*)d_in[6];
    const float* ar2 = (const float*)d_in[7];
    const float* b2v = (const float*)d_in[8];
    const int* srcA  = (const int*)d_in[9];
    const int* dstA  = (const int*)d_in[10];
    int E = in_sizes[9];

    char* ws = (char*)d_ws;
    int* counts   = (int*)(ws);                       // 16 KB
    int* cursor   = (int*)(ws + 16384);               // 16 KB
    int* rowstart = (int*)(ws + 32768);               // 16.4 KB
    int* nbr      = (int*)(ws + 65536);               // E*4
    size_t fa = (65536 + (size_t)E * 4 + 255) & ~(size_t)255;
    float* feat1 = (float*)(ws + fa);                                   // 8.39 MB
    float* el1   = (float*)(ws + fa + 8388608);                         // 1.05 MB
    float* er1   = (float*)(ws + fa + 8388608 + 1048576);               // 1.05 MB
    float* h1    = (float*)(ws + fa + 8388608 + 2097152);               // 8.39 MB
    float* feat2 = (float*)(ws + fa + 8388608 + 2097152 + 8388608);     // 16.78 MB
    float* el2   = (float*)(ws + fa + 35651584);                        // 0.26 MB
    float* er2   = (float*)(ws + fa + 35651584 + 262144);               // 0.26 MB
    float* out2  = feat1;  // alias: feat1/el1/er1/h1 (18.9 MB) dead before k_attn2 writes

    float* out = (float*)d_out;

    dim3 blk(256);
    // CSR build
    k_zero<<<dim3((N_NODES + 255) / 256), blk, 0, stream>>>(counts, cursor);
    k_count<<<dim3((E + 255) / 256), blk, 0, stream>>>(dstA, E, counts);
    k_scan<<<dim3(1), blk, 0, stream>>>(counts, rowstart);
    k_fill<<<dim3((E + 255) / 256), blk, 0, stream>>>(srcA, dstA, E, rowstart, cursor, nbr);

    // layer 1
    k_feat1<<<dim3(N_NODES / 256, BATCH), blk, 0, stream>>>(x, W1, al1, ar1, feat1, el1, er1);
    k_attn1<<<dim3(N_NODES / 64, BATCH), blk, 0, stream>>>(el1, er1, feat1, rowstart, nbr, b1v, h1);

    // layer 2
    k_feat2<<<dim3(N_NODES / 4, BATCH), blk, 0, stream>>>(h1, W2, al2, ar2, feat2, el2, er2);
    k_attn2<<<dim3(N_NODES / 4, BATCH), blk, 0, stream>>>(el2, er2, feat2, rowstart, nbr, b2v, out2);

    // output transpose
    k_trans<<<dim3(N_NODES / 64, BATCH), blk, 0, stream>>>(out2, out);
}